// Round 1
// baseline (2341.227 us; speedup 1.0000x reference)
//
#include <hip/hip_runtime.h>
#include <math.h>

#define BB 16
#define CC 64
#define HH 128
#define WW 256
#define HWs 32768      // HH*WW
#define NN 524288      // BB*HH*WW
#define KMAX 8192

// ---- workspace layout (bytes) ----
#define OFF_CMEAN   0                                  // f32 [3][NN]
#define OFF_PARENT  (OFF_CMEAN  + 3*NN*4)              // u32 [3][NN]
#define OFF_DENSE   (OFF_PARENT + 3*NN*4)              // u32 [3][NN]
#define OFF_COUNTS  (OFF_DENSE  + 3*NN*4)              // i32 [3][BB][KMAX]
#define OFF_ROOTLAB (OFF_COUNTS + 3*BB*KMAX*4)         // u32 [3][KMAX]
#define OFF_MMKEY   (OFF_ROOTLAB+ 3*KMAX*4)            // u32 [3][BB][2]  (minkey,maxkey)
#define OFF_K       (OFF_MMKEY  + 3*BB*2*4)            // u32 [3] (+pad)
#define OFF_BEST    (OFF_K      + 16)                  // u32 [3][BB]
#define OFF_CENT    (OFF_BEST   + 3*BB*4)              // i32 [3][BB][3]
#define OFF_END     (OFF_CENT   + 3*BB*3*4)

// monotone float<->uint key (order-preserving incl. negatives)
__device__ __forceinline__ unsigned f2key(float f) {
    unsigned u = __float_as_uint(f);
    return (u & 0x80000000u) ? ~u : (u | 0x80000000u);
}
__device__ __forceinline__ float key2f(unsigned k) {
    unsigned u = (k & 0x80000000u) ? (k ^ 0x80000000u) : ~k;
    return __uint_as_float(u);
}

// ---- union-find, links always point to LARGER index => root = max linear idx ----
__device__ unsigned uf_find(unsigned* p, unsigned i) {
    while (true) {
        unsigned pi = ((volatile unsigned*)p)[i];
        if (pi == i) return i;
        unsigned gp = ((volatile unsigned*)p)[pi];
        if (gp != pi) ((volatile unsigned*)p)[i] = gp;  // path halving (monotone, safe)
        i = pi;
    }
}
__device__ void uf_union(unsigned* p, unsigned a, unsigned b) {
    while (true) {
        a = uf_find(p, a);
        b = uf_find(p, b);
        if (a == b) return;
        if (a < b) { unsigned t = a; a = b; b = t; }   // a = max root
        unsigned old = atomicCAS(&p[b], b, a);
        if (old == b) return;
        b = old;
    }
}

__global__ void k_init(unsigned* mmkey) {
    int t = threadIdx.x;
    if (t < 3 * BB) mmkey[t * 2] = 0xFFFFFFFFu;  // min-key sentinel (max-key=0 from memset)
}

// channel mean + per-sample min/max
__global__ void k_cmean(const float* __restrict__ x0, const float* __restrict__ x1,
                        const float* __restrict__ x2, float* __restrict__ cmean,
                        unsigned* __restrict__ mmkey) {
    int z = blockIdx.z, b = blockIdx.y, t = threadIdx.x;
    const float* x = (z == 0) ? x0 : (z == 1) ? x1 : x2;
    int hw4 = (blockIdx.x * blockDim.x + t) * 4;
    size_t base = (size_t)b * CC * HWs + hw4;
    float4 s = make_float4(0.f, 0.f, 0.f, 0.f);
#pragma unroll 4
    for (int c = 0; c < CC; c++) {
        float4 v = *reinterpret_cast<const float4*>(x + base + (size_t)c * HWs);
        s.x += v.x; s.y += v.y; s.z += v.z; s.w += v.w;
    }
    const float inv = 1.f / 64.f;   // /64 is exact pow2, identical to mean
    s.x *= inv; s.y *= inv; s.z *= inv; s.w *= inv;
    *reinterpret_cast<float4*>(cmean + (size_t)z * NN + (size_t)b * HWs + hw4) = s;

    float mn = fminf(fminf(s.x, s.y), fminf(s.z, s.w));
    float mx = fmaxf(fmaxf(s.x, s.y), fmaxf(s.z, s.w));
    for (int o = 32; o; o >>= 1) {
        mn = fminf(mn, __shfl_down(mn, o));
        mx = fmaxf(mx, __shfl_down(mx, o));
    }
    __shared__ float smn[4], smx[4];
    int wid = t >> 6, lane = t & 63;
    if (lane == 0) { smn[wid] = mn; smx[wid] = mx; }
    __syncthreads();
    if (t == 0) {
        mn = fminf(fminf(smn[0], smn[1]), fminf(smn[2], smn[3]));
        mx = fmaxf(fmaxf(smx[0], smx[1]), fmaxf(smx[2], smx[3]));
        atomicMin(&mmkey[(z * BB + b) * 2 + 0], f2key(mn));
        atomicMax(&mmkey[(z * BB + b) * 2 + 1], f2key(mx));
    }
}

// normalize -> mask -> parent init (i if masked, ~0 otherwise)
__global__ void k_mask(const float* __restrict__ cmean, const unsigned* __restrict__ mmkey,
                       unsigned* __restrict__ parent) {
    int z = blockIdx.y;
    int i = blockIdx.x * 256 + threadIdx.x;
    int b = i >> 15;
    float mn = key2f(mmkey[(z * BB + b) * 2 + 0]);
    float mx = key2f(mmkey[(z * BB + b) * 2 + 1]);
    float c = cmean[(size_t)z * NN + i];
    float v = (c - mn) / (mx - mn);
    parent[(size_t)z * NN + i] = (v >= 0.4f) ? (unsigned)i : 0xFFFFFFFFu;
}

__global__ void k_merge(unsigned* __restrict__ parent_all) {
    int z = blockIdx.y;
    unsigned* p = parent_all + (size_t)z * NN;
    unsigned i = blockIdx.x * 256 + threadIdx.x;
    if (p[i] == 0xFFFFFFFFu) return;
    int w = i & (WW - 1), h = (i >> 8) & (HH - 1), b = i >> 15;
    if (w < WW - 1 && p[i + 1]   != 0xFFFFFFFFu) uf_union(p, i, i + 1);
    if (h < HH - 1 && p[i + WW]  != 0xFFFFFFFFu) uf_union(p, i, i + WW);
    if (b < BB - 1 && p[i + HWs] != 0xFFFFFFFFu) uf_union(p, i, i + HWs);
}

__global__ void k_compress(unsigned* __restrict__ parent_all, unsigned* __restrict__ dense_all,
                           unsigned* __restrict__ rootlab, unsigned* __restrict__ Kc) {
    int z = blockIdx.y;
    unsigned* p = parent_all + (size_t)z * NN;
    unsigned i = blockIdx.x * 256 + threadIdx.x;
    if (p[i] == 0xFFFFFFFFu) return;
    unsigned r = uf_find(p, i);
    p[i] = r;
    if (r == i) {
        unsigned id = atomicAdd(&Kc[z], 1u);
        if (id >= KMAX) id = KMAX - 1;   // never expected (components ~ tens)
        dense_all[(size_t)z * NN + i] = id;
        rootlab[z * KMAX + id] = i;
    }
}

// per-slice per-component counts, wave-aggregated atomics
__global__ void k_count(const unsigned* __restrict__ parent_all,
                        const unsigned* __restrict__ dense_all, int* __restrict__ counts) {
    int z = blockIdx.y;
    const unsigned* p = parent_all + (size_t)z * NN;
    const unsigned* d = dense_all + (size_t)z * NN;
    int i = blockIdx.x * 256 + threadIdx.x;
    int b = i >> 15;   // uniform across the wave (64 | HWs)
    unsigned pi = p[i];
    bool valid = (pi != 0xFFFFFFFFu);
    int id = valid ? (int)d[pi] : -1;
    int lane = threadIdx.x & 63;
    int* crow = counts + ((size_t)z * BB + b) * KMAX;
    unsigned long long rem = __ballot(valid);
    while (rem) {
        int leader = __ffsll(rem) - 1;
        int lid = __shfl(id, leader);
        unsigned long long m = __ballot(valid && id == lid) & rem;
        if (lane == leader) atomicAdd(&crow[lid], (int)__popcll(m));
        rem &= ~m;
    }
}

// per-slice argmax: max count, tie -> smallest root label (== reference argmax semantics)
__global__ void k_best(const int* __restrict__ counts, const unsigned* __restrict__ rootlab,
                       const unsigned* __restrict__ Kc, unsigned* __restrict__ best) {
    int z = blockIdx.y, b = blockIdx.x, t = threadIdx.x;
    const int* crow = counts + ((size_t)z * BB + b) * KMAX;
    const unsigned* rl = rootlab + z * KMAX;
    unsigned K = Kc[z]; if (K > KMAX) K = KMAX;
    int bc = -1; unsigned brl = 0xFFFFFFFFu; int bj = 0;
    for (unsigned j = t; j < K; j += blockDim.x) {
        int c = crow[j]; unsigned r = rl[j];
        if (c > bc || (c == bc && r < brl)) { bc = c; brl = r; bj = (int)j; }
    }
    __shared__ int sc[256]; __shared__ unsigned sr[256]; __shared__ int sj[256];
    sc[t] = bc; sr[t] = brl; sj[t] = bj;
    __syncthreads();
    for (int o = 128; o; o >>= 1) {
        if (t < o) {
            int c2 = sc[t + o]; unsigned r2 = sr[t + o];
            if (c2 > sc[t] || (c2 == sc[t] && r2 < sr[t])) { sc[t] = c2; sr[t] = r2; sj[t] = sj[t + o]; }
        }
        __syncthreads();
    }
    if (t == 0) best[z * BB + b] = (unsigned)sj[0];
}

// masked normalized output + integer centroid sums
__global__ void k_result(const float* __restrict__ cmean, const unsigned* __restrict__ parent_all,
                         const unsigned* __restrict__ dense_all, const unsigned* __restrict__ mmkey,
                         const unsigned* __restrict__ best, float* __restrict__ out,
                         int* __restrict__ cent) {
    int z = blockIdx.y;
    int i = blockIdx.x * 256 + threadIdx.x;
    int b = i >> 15;
    const unsigned* p = parent_all + (size_t)z * NN;
    unsigned pi = p[i];
    bool big = false;
    if (pi != 0xFFFFFFFFu) big = (dense_all[(size_t)z * NN + pi] == best[z * BB + b]);
    float mn = key2f(mmkey[(z * BB + b) * 2 + 0]);
    float mx = key2f(mmkey[(z * BB + b) * 2 + 1]);
    float c = cmean[(size_t)z * NN + i];
    float v = (c - mn) / (mx - mn);
    out[32 + (size_t)z * NN + i] = big ? v : 0.f;

    int c1 = big ? 1 : 0;
    int ch = big ? ((i >> 8) & (HH - 1)) : 0;
    int cw = big ? (i & (WW - 1)) : 0;
    for (int o = 32; o; o >>= 1) {
        c1 += __shfl_down(c1, o); ch += __shfl_down(ch, o); cw += __shfl_down(cw, o);
    }
    __shared__ int s0[4], s1[4], s2[4];
    int wid = threadIdx.x >> 6, lane = threadIdx.x & 63;
    if (lane == 0) { s0[wid] = c1; s1[wid] = ch; s2[wid] = cw; }
    __syncthreads();
    if (threadIdx.x == 0) {
        c1 = s0[0] + s0[1] + s0[2] + s0[3];
        ch = s1[0] + s1[1] + s1[2] + s1[3];
        cw = s2[0] + s2[1] + s2[2] + s2[3];
        int* ct = cent + (z * BB + b) * 3;
        atomicAdd(&ct[0], c1); atomicAdd(&ct[1], ch); atomicAdd(&ct[2], cw);
    }
}

__global__ void k_final(const int* __restrict__ cent, float* __restrict__ out) {
    int b = threadIdx.x;
    if (b >= BB) return;
    const float PI = (float)M_PI;  // f32(np.pi)
    float th[3], ph[3];
    for (int z = 0; z < 3; z++) {
        const int* ct = cent + (z * BB + b) * 3;
        float cnt = (float)ct[0];
        float hm = (float)ct[1] / cnt;   // integer sums exact in f32 (< 2^24)
        float wm = (float)ct[2] / cnt;
        ph[z] = (0.5f - hm / (float)HH) * PI;
        th[z] = (wm / (float)WW - 0.5f) * 2.0f * PI;
    }
    auto dist = [PI](float t1, float p1, float t2, float p2) {
        float cosd = sinf(t1) * sinf(t2) + cosf(t1) * cosf(t2) * cosf(p1 - p2);
        float d = acosf(cosd);
        if (isnan(d)) d = 0.f;           // jnp.nan_to_num semantics
        return d / PI;
    };
    out[b]      = dist(th[0], ph[0], th[1], ph[1]);
    out[BB + b] = dist(th[1], ph[1], th[2], ph[2]);
}

extern "C" void kernel_launch(void* const* d_in, const int* in_sizes, int n_in,
                              void* d_out, int out_size, void* d_ws, size_t ws_size,
                              hipStream_t stream) {
    const float* x0 = (const float*)d_in[0];
    const float* x1 = (const float*)d_in[1];
    const float* x2 = (const float*)d_in[2];
    float* out = (float*)d_out;
    char* ws = (char*)d_ws;
    float*    cmean   = (float*)(ws + OFF_CMEAN);
    unsigned* parent  = (unsigned*)(ws + OFF_PARENT);
    unsigned* dense   = (unsigned*)(ws + OFF_DENSE);
    int*      counts  = (int*)(ws + OFF_COUNTS);
    unsigned* rootlab = (unsigned*)(ws + OFF_ROOTLAB);
    unsigned* mmkey   = (unsigned*)(ws + OFF_MMKEY);
    unsigned* Kc      = (unsigned*)(ws + OFF_K);
    unsigned* best    = (unsigned*)(ws + OFF_BEST);
    int*      cent    = (int*)(ws + OFF_CENT);

    hipMemsetAsync(ws + OFF_COUNTS, 0, OFF_END - OFF_COUNTS, stream);
    hipLaunchKernelGGL(k_init, dim3(1), dim3(64), 0, stream, mmkey);
    hipLaunchKernelGGL(k_cmean, dim3(HWs / 1024, BB, 3), dim3(256), 0, stream,
                       x0, x1, x2, cmean, mmkey);
    hipLaunchKernelGGL(k_mask, dim3(NN / 256, 3), dim3(256), 0, stream, cmean, mmkey, parent);
    hipLaunchKernelGGL(k_merge, dim3(NN / 256, 3), dim3(256), 0, stream, parent);
    hipLaunchKernelGGL(k_compress, dim3(NN / 256, 3), dim3(256), 0, stream,
                       parent, dense, rootlab, Kc);
    hipLaunchKernelGGL(k_count, dim3(NN / 256, 3), dim3(256), 0, stream, parent, dense, counts);
    hipLaunchKernelGGL(k_best, dim3(BB, 3), dim3(256), 0, stream, counts, rootlab, Kc, best);
    hipLaunchKernelGGL(k_result, dim3(NN / 256, 3), dim3(256), 0, stream,
                       cmean, parent, dense, mmkey, best, out, cent);
    hipLaunchKernelGGL(k_final, dim3(1), dim3(64), 0, stream, cent, out);
}

// Round 2
// 1180.835 us; speedup vs baseline: 1.9827x; 1.9827x over previous
//
#include <hip/hip_runtime.h>
#include <math.h>

#define BB 16
#define CC 64
#define HH 128
#define WW 256
#define HWs 32768      // HH*WW
#define NN 524288      // BB*HH*WW
#define KMAX 8192
#define INV 0xFFFFFFFFu

// tile: full batch depth x 8h x 32w = 4096 voxels
#define TILE_H 8
#define TILE_W 32
#define TVOX 4096
#define NWEDGE 14336   // 7 internal w-boundaries * 16b * 128h
#define NHEDGE 61440   // 15 internal h-boundaries * 16b * 256w
#define NEDGE  75776

// ---- workspace layout (bytes) ----
#define OFF_CMEAN   0                                  // f32 [3][NN]
#define OFF_PARENT  (OFF_CMEAN  + 3*NN*4)              // u32 [3][NN]
#define OFF_DENSE   (OFF_PARENT + 3*NN*4)              // u32 [3][NN]
#define OFF_COUNTS  (OFF_DENSE  + 3*NN*4)              // i32 [3][BB][KMAX]
#define OFF_ROOTLAB (OFF_COUNTS + 3*BB*KMAX*4)         // u32 [3][KMAX]
#define OFF_MMKEY   (OFF_ROOTLAB+ 3*KMAX*4)            // u32 [3][BB][2]  (minkey,maxkey)
#define OFF_K       (OFF_MMKEY  + 3*BB*2*4)            // u32 [3] (+pad)
#define OFF_BEST    (OFF_K      + 16)                  // u32 [3][BB]
#define OFF_CENT    (OFF_BEST   + 3*BB*4)              // i32 [3][BB][3]
#define OFF_END     (OFF_CENT   + 3*BB*3*4)

// monotone float<->uint key (order-preserving incl. negatives)
__device__ __forceinline__ unsigned f2key(float f) {
    unsigned u = __float_as_uint(f);
    return (u & 0x80000000u) ? ~u : (u | 0x80000000u);
}
__device__ __forceinline__ float key2f(unsigned k) {
    unsigned u = (k & 0x80000000u) ? (k ^ 0x80000000u) : ~k;
    return __uint_as_float(u);
}

// ---- union-find, links always point to LARGER index => root = max linear idx ----
__device__ unsigned uf_find(unsigned* p, unsigned i) {
    while (true) {
        unsigned pi = ((volatile unsigned*)p)[i];
        if (pi == i) return i;
        unsigned gp = ((volatile unsigned*)p)[pi];
        if (gp != pi) ((volatile unsigned*)p)[i] = gp;  // path halving (monotone, safe)
        i = pi;
    }
}
__device__ void uf_union(unsigned* p, unsigned a, unsigned b) {
    while (true) {
        a = uf_find(p, a);
        b = uf_find(p, b);
        if (a == b) return;
        if (a < b) { unsigned t = a; a = b; b = t; }   // a = max root
        unsigned old = atomicCAS(&p[b], b, a);
        if (old == b) return;
        b = old;
    }
}

// ---- LDS union-find (same invariants, shared-memory atomics) ----
__device__ __forceinline__ unsigned lfind(unsigned* p, unsigned i) {
    while (true) {
        unsigned pi = ((volatile unsigned*)p)[i];
        if (pi == i) return i;
        unsigned gp = ((volatile unsigned*)p)[pi];
        if (gp != pi) ((volatile unsigned*)p)[i] = gp;
        i = pi;
    }
}
__device__ void lunion(unsigned* p, unsigned a, unsigned b) {
    while (true) {
        a = lfind(p, a);
        b = lfind(p, b);
        if (a == b) return;
        if (a < b) { unsigned t = a; a = b; b = t; }
        unsigned old = atomicCAS(&p[b], b, a);
        if (old == b) return;
        b = old;
    }
}

__global__ void k_init(unsigned* mmkey) {
    int t = threadIdx.x;
    if (t < 3 * BB) mmkey[t * 2] = INV;  // min-key sentinel (max-key=0 from memset)
}

// channel mean + per-sample min/max
__global__ void k_cmean(const float* __restrict__ x0, const float* __restrict__ x1,
                        const float* __restrict__ x2, float* __restrict__ cmean,
                        unsigned* __restrict__ mmkey) {
    int z = blockIdx.z, b = blockIdx.y, t = threadIdx.x;
    const float* x = (z == 0) ? x0 : (z == 1) ? x1 : x2;
    int hw4 = (blockIdx.x * blockDim.x + t) * 4;
    size_t base = (size_t)b * CC * HWs + hw4;
    float4 s = make_float4(0.f, 0.f, 0.f, 0.f);
#pragma unroll 4
    for (int c = 0; c < CC; c++) {
        float4 v = *reinterpret_cast<const float4*>(x + base + (size_t)c * HWs);
        s.x += v.x; s.y += v.y; s.z += v.z; s.w += v.w;
    }
    const float inv = 1.f / 64.f;   // /64 is exact pow2, identical to mean
    s.x *= inv; s.y *= inv; s.z *= inv; s.w *= inv;
    *reinterpret_cast<float4*>(cmean + (size_t)z * NN + (size_t)b * HWs + hw4) = s;

    float mn = fminf(fminf(s.x, s.y), fminf(s.z, s.w));
    float mx = fmaxf(fmaxf(s.x, s.y), fmaxf(s.z, s.w));
    for (int o = 32; o; o >>= 1) {
        mn = fminf(mn, __shfl_down(mn, o));
        mx = fmaxf(mx, __shfl_down(mx, o));
    }
    __shared__ float smn[4], smx[4];
    int wid = t >> 6, lane = t & 63;
    if (lane == 0) { smn[wid] = mn; smx[wid] = mx; }
    __syncthreads();
    if (t == 0) {
        mn = fminf(fminf(smn[0], smn[1]), fminf(smn[2], smn[3]));
        mx = fmaxf(fmaxf(smx[0], smx[1]), fmaxf(smx[2], smx[3]));
        atomicMin(&mmkey[(z * BB + b) * 2 + 0], f2key(mn));
        atomicMax(&mmkey[(z * BB + b) * 2 + 1], f2key(mx));
    }
}

// fused: normalize -> mask -> LOCAL (in-LDS) CCL over a [16b x 8h x 32w] tile
// -> write global parent pointing at local-root's global index.
// Local li = b*256 + lh*32 + lw is lexicographically order-identical to the
// global linear index within the tile, so local max-root == global max-root
// within the tile; global boundary unions then preserve root = component max.
__global__ void __launch_bounds__(256) k_mask_ccl(const float* __restrict__ cmean,
                                                  const unsigned* __restrict__ mmkey,
                                                  unsigned* __restrict__ parent_all) {
    int z = blockIdx.z;
    int h0 = blockIdx.y * TILE_H;
    int w0 = blockIdx.x * TILE_W;
    int t = threadIdx.x;
    __shared__ unsigned sp[TVOX];
    __shared__ float smn[BB], smx[BB];
    if (t < BB) {
        smn[t] = key2f(mmkey[(z * BB + t) * 2 + 0]);
        smx[t] = key2f(mmkey[(z * BB + t) * 2 + 1]);
    }
    __syncthreads();
#pragma unroll
    for (int ph = 0; ph < TVOX / 256; ph++) {
        int li = ph * 256 + t;
        int lb = li >> 8, lh = (li >> 5) & 7, lw = li & 31;
        unsigned gi = lb * HWs + (h0 + lh) * WW + (w0 + lw);
        float c = cmean[(size_t)z * NN + gi];
        float v = (c - smn[lb]) / (smx[lb] - smn[lb]);
        sp[li] = (v >= 0.4f) ? (unsigned)li : INV;
    }
    __syncthreads();
#pragma unroll
    for (int ph = 0; ph < TVOX / 256; ph++) {
        int li = ph * 256 + t;
        if (sp[li] == INV) continue;            // INV entries are never written
        int lb = li >> 8, lh = (li >> 5) & 7, lw = li & 31;
        if (lw < TILE_W - 1 && sp[li + 1]   != INV) lunion(sp, li, li + 1);
        if (lh < TILE_H - 1 && sp[li + 32]  != INV) lunion(sp, li, li + 32);
        if (lb < BB - 1     && sp[li + 256] != INV) lunion(sp, li, li + 256);
    }
    __syncthreads();
#pragma unroll
    for (int ph = 0; ph < TVOX / 256; ph++) {
        int li = ph * 256 + t;
        int lb = li >> 8, lh = (li >> 5) & 7, lw = li & 31;
        unsigned gi = lb * HWs + (h0 + lh) * WW + (w0 + lw);
        unsigned v = sp[li];
        if (v != INV) {
            unsigned r = li;
            while (sp[r] != r) r = sp[r];       // quiescent after barrier
            int rb = r >> 8, rh = (r >> 5) & 7, rw = r & 31;
            v = rb * HWs + (h0 + rh) * WW + (w0 + rw);
        }
        parent_all[(size_t)z * NN + gi] = v;
    }
}

// global unions only across tile boundaries, with run-leader dedup
__global__ void k_merge_bnd(unsigned* __restrict__ parent_all) {
    int z = blockIdx.y;
    unsigned* p = parent_all + (size_t)z * NN;
    int e = blockIdx.x * 256 + threadIdx.x;
    if (e >= NEDGE) return;
    unsigned i, j;
    bool lead = true;
    if (e < NWEDGE) {
        int k = e % 7, rest = e / 7;           // rest = b*128 + h
        int h = rest & (HH - 1), b = rest >> 7;
        int w = k * TILE_W + (TILE_W - 1);
        i = b * HWs + h * WW + w; j = i + 1;
        if ((h & (TILE_H - 1)) != 0)           // prev-h pair in same tiles?
            if (p[i - WW] != INV && p[j - WW] != INV) lead = false;
    } else {
        int e2 = e - NWEDGE;
        int k = e2 % 15, rest = e2 / 15;       // rest = b*256 + w
        int w = rest & (WW - 1), b = rest >> 8;
        int h = k * TILE_H + (TILE_H - 1);
        i = b * HWs + h * WW + w; j = i + WW;
        if ((w & (TILE_W - 1)) != 0)
            if (p[i - 1] != INV && p[j - 1] != INV) lead = false;
    }
    if (lead && p[i] != INV && p[j] != INV) uf_union(p, i, j);
}

__global__ void k_compress(unsigned* __restrict__ parent_all, unsigned* __restrict__ dense_all,
                           unsigned* __restrict__ rootlab, unsigned* __restrict__ Kc) {
    int z = blockIdx.y;
    unsigned* p = parent_all + (size_t)z * NN;
    unsigned i = blockIdx.x * 256 + threadIdx.x;
    if (p[i] == INV) return;
    unsigned r = uf_find(p, i);
    p[i] = r;
    if (r == i) {
        unsigned id = atomicAdd(&Kc[z], 1u);
        if (id >= KMAX) id = KMAX - 1;   // never expected (components ~ tens)
        dense_all[(size_t)z * NN + i] = id;
        rootlab[z * KMAX + id] = i;
    }
}

// per-slice per-component counts, wave-aggregated atomics
__global__ void k_count(const unsigned* __restrict__ parent_all,
                        const unsigned* __restrict__ dense_all, int* __restrict__ counts) {
    int z = blockIdx.y;
    const unsigned* p = parent_all + (size_t)z * NN;
    const unsigned* d = dense_all + (size_t)z * NN;
    int i = blockIdx.x * 256 + threadIdx.x;
    int b = i >> 15;   // uniform across the wave (64 | HWs)
    unsigned pi = p[i];
    bool valid = (pi != INV);
    int id = valid ? (int)d[pi] : -1;
    int lane = threadIdx.x & 63;
    int* crow = counts + ((size_t)z * BB + b) * KMAX;
    unsigned long long rem = __ballot(valid);
    while (rem) {
        int leader = __ffsll(rem) - 1;
        int lid = __shfl(id, leader);
        unsigned long long m = __ballot(valid && id == lid) & rem;
        if (lane == leader) atomicAdd(&crow[lid], (int)__popcll(m));
        rem &= ~m;
    }
}

// per-slice argmax: max count, tie -> smallest root label (== reference argmax semantics)
__global__ void k_best(const int* __restrict__ counts, const unsigned* __restrict__ rootlab,
                       const unsigned* __restrict__ Kc, unsigned* __restrict__ best) {
    int z = blockIdx.y, b = blockIdx.x, t = threadIdx.x;
    const int* crow = counts + ((size_t)z * BB + b) * KMAX;
    const unsigned* rl = rootlab + z * KMAX;
    unsigned K = Kc[z]; if (K > KMAX) K = KMAX;
    int bc = -1; unsigned brl = INV; int bj = 0;
    for (unsigned j = t; j < K; j += blockDim.x) {
        int c = crow[j]; unsigned r = rl[j];
        if (c > bc || (c == bc && r < brl)) { bc = c; brl = r; bj = (int)j; }
    }
    __shared__ int sc[256]; __shared__ unsigned sr[256]; __shared__ int sj[256];
    sc[t] = bc; sr[t] = brl; sj[t] = bj;
    __syncthreads();
    for (int o = 128; o; o >>= 1) {
        if (t < o) {
            int c2 = sc[t + o]; unsigned r2 = sr[t + o];
            if (c2 > sc[t] || (c2 == sc[t] && r2 < sr[t])) { sc[t] = c2; sr[t] = r2; sj[t] = sj[t + o]; }
        }
        __syncthreads();
    }
    if (t == 0) best[z * BB + b] = (unsigned)sj[0];
}

// masked normalized output + integer centroid sums
__global__ void k_result(const float* __restrict__ cmean, const unsigned* __restrict__ parent_all,
                         const unsigned* __restrict__ dense_all, const unsigned* __restrict__ mmkey,
                         const unsigned* __restrict__ best, float* __restrict__ out,
                         int* __restrict__ cent) {
    int z = blockIdx.y;
    int i = blockIdx.x * 256 + threadIdx.x;
    int b = i >> 15;
    const unsigned* p = parent_all + (size_t)z * NN;
    unsigned pi = p[i];
    bool big = false;
    if (pi != INV) big = (dense_all[(size_t)z * NN + pi] == best[z * BB + b]);
    float mn = key2f(mmkey[(z * BB + b) * 2 + 0]);
    float mx = key2f(mmkey[(z * BB + b) * 2 + 1]);
    float c = cmean[(size_t)z * NN + i];
    float v = (c - mn) / (mx - mn);
    out[32 + (size_t)z * NN + i] = big ? v : 0.f;

    int c1 = big ? 1 : 0;
    int ch = big ? ((i >> 8) & (HH - 1)) : 0;
    int cw = big ? (i & (WW - 1)) : 0;
    for (int o = 32; o; o >>= 1) {
        c1 += __shfl_down(c1, o); ch += __shfl_down(ch, o); cw += __shfl_down(cw, o);
    }
    __shared__ int s0[4], s1[4], s2[4];
    int wid = threadIdx.x >> 6, lane = threadIdx.x & 63;
    if (lane == 0) { s0[wid] = c1; s1[wid] = ch; s2[wid] = cw; }
    __syncthreads();
    if (threadIdx.x == 0) {
        c1 = s0[0] + s0[1] + s0[2] + s0[3];
        ch = s1[0] + s1[1] + s1[2] + s1[3];
        cw = s2[0] + s2[1] + s2[2] + s2[3];
        int* ct = cent + (z * BB + b) * 3;
        atomicAdd(&ct[0], c1); atomicAdd(&ct[1], ch); atomicAdd(&ct[2], cw);
    }
}

__global__ void k_final(const int* __restrict__ cent, float* __restrict__ out) {
    int b = threadIdx.x;
    if (b >= BB) return;
    const float PI = (float)M_PI;  // f32(np.pi)
    float th[3], ph[3];
    for (int z = 0; z < 3; z++) {
        const int* ct = cent + (z * BB + b) * 3;
        float cnt = (float)ct[0];
        float hm = (float)ct[1] / cnt;   // integer sums exact in f32 (< 2^24)
        float wm = (float)ct[2] / cnt;
        ph[z] = (0.5f - hm / (float)HH) * PI;
        th[z] = (wm / (float)WW - 0.5f) * 2.0f * PI;
    }
    auto dist = [PI](float t1, float p1, float t2, float p2) {
        float cosd = sinf(t1) * sinf(t2) + cosf(t1) * cosf(t2) * cosf(p1 - p2);
        float d = acosf(cosd);
        if (isnan(d)) d = 0.f;           // jnp.nan_to_num semantics
        return d / PI;
    };
    out[b]      = dist(th[0], ph[0], th[1], ph[1]);
    out[BB + b] = dist(th[1], ph[1], th[2], ph[2]);
}

extern "C" void kernel_launch(void* const* d_in, const int* in_sizes, int n_in,
                              void* d_out, int out_size, void* d_ws, size_t ws_size,
                              hipStream_t stream) {
    const float* x0 = (const float*)d_in[0];
    const float* x1 = (const float*)d_in[1];
    const float* x2 = (const float*)d_in[2];
    float* out = (float*)d_out;
    char* ws = (char*)d_ws;
    float*    cmean   = (float*)(ws + OFF_CMEAN);
    unsigned* parent  = (unsigned*)(ws + OFF_PARENT);
    unsigned* dense   = (unsigned*)(ws + OFF_DENSE);
    int*      counts  = (int*)(ws + OFF_COUNTS);
    unsigned* rootlab = (unsigned*)(ws + OFF_ROOTLAB);
    unsigned* mmkey   = (unsigned*)(ws + OFF_MMKEY);
    unsigned* Kc      = (unsigned*)(ws + OFF_K);
    unsigned* best    = (unsigned*)(ws + OFF_BEST);
    int*      cent    = (int*)(ws + OFF_CENT);

    hipMemsetAsync(ws + OFF_COUNTS, 0, OFF_END - OFF_COUNTS, stream);
    hipLaunchKernelGGL(k_init, dim3(1), dim3(64), 0, stream, mmkey);
    hipLaunchKernelGGL(k_cmean, dim3(HWs / 1024, BB, 3), dim3(256), 0, stream,
                       x0, x1, x2, cmean, mmkey);
    hipLaunchKernelGGL(k_mask_ccl, dim3(WW / TILE_W, HH / TILE_H, 3), dim3(256), 0, stream,
                       cmean, mmkey, parent);
    hipLaunchKernelGGL(k_merge_bnd, dim3((NEDGE + 255) / 256, 3), dim3(256), 0, stream, parent);
    hipLaunchKernelGGL(k_compress, dim3(NN / 256, 3), dim3(256), 0, stream,
                       parent, dense, rootlab, Kc);
    hipLaunchKernelGGL(k_count, dim3(NN / 256, 3), dim3(256), 0, stream, parent, dense, counts);
    hipLaunchKernelGGL(k_best, dim3(BB, 3), dim3(256), 0, stream, counts, rootlab, Kc, best);
    hipLaunchKernelGGL(k_result, dim3(NN / 256, 3), dim3(256), 0, stream,
                       cmean, parent, dense, mmkey, best, out, cent);
    hipLaunchKernelGGL(k_final, dim3(1), dim3(64), 0, stream, cent, out);
}

// Round 3
// 669.018 us; speedup vs baseline: 3.4995x; 1.7650x over previous
//
#include <hip/hip_runtime.h>
#include <math.h>

#define BB 16
#define CC 64
#define HH 128
#define WW 256
#define HWs 32768      // HH*WW
#define NN 524288      // BB*HH*WW
#define KMAX 8192
#define INV 0xFFFFFFFFu

// tile: full batch depth x 8h x 32w = 4096 voxels
#define TILE_H 8
#define TILE_W 32
#define TVOX 4096
#define NROWS 128      // BB * TILE_H rows of 32 w-bits
#define NWEDGE 14336   // 7 internal w-boundaries * 16b * 128h
#define NHEDGE 61440   // 15 internal h-boundaries * 16b * 256w
#define NEDGE  75776

// ---- workspace layout (bytes) ----
#define OFF_CMEAN   0                                  // f32 [3][NN]
#define OFF_PARENT  (OFF_CMEAN  + 3*NN*4)              // u32 [3][NN]
#define OFF_DENSE   (OFF_PARENT + 3*NN*4)              // u32 [3][NN]
#define OFF_COUNTS  (OFF_DENSE  + 3*NN*4)              // i32 [3][BB][KMAX]
#define OFF_ROOTLAB (OFF_COUNTS + 3*BB*KMAX*4)         // u32 [3][KMAX]
#define OFF_MMKEY   (OFF_ROOTLAB+ 3*KMAX*4)            // u32 [3][BB][2]  (minkey,maxkey)
#define OFF_K       (OFF_MMKEY  + 3*BB*2*4)            // u32 [3] (+pad)
#define OFF_BEST    (OFF_K      + 16)                  // u32 [3][BB]
#define OFF_CENT    (OFF_BEST   + 3*BB*4)              // i32 [3][BB][3]
#define OFF_END     (OFF_CENT   + 3*BB*3*4)

// monotone float<->uint key (order-preserving incl. negatives)
__device__ __forceinline__ unsigned f2key(float f) {
    unsigned u = __float_as_uint(f);
    return (u & 0x80000000u) ? ~u : (u | 0x80000000u);
}
__device__ __forceinline__ float key2f(unsigned k) {
    unsigned u = (k & 0x80000000u) ? (k ^ 0x80000000u) : ~k;
    return __uint_as_float(u);
}

// ---- union-find, links always point to LARGER index => root = max linear idx ----
__device__ unsigned uf_find(unsigned* p, unsigned i) {
    while (true) {
        unsigned pi = ((volatile unsigned*)p)[i];
        if (pi == i) return i;
        unsigned gp = ((volatile unsigned*)p)[pi];
        if (gp != pi) ((volatile unsigned*)p)[i] = gp;  // path halving (monotone, safe)
        i = pi;
    }
}
__device__ void uf_union(unsigned* p, unsigned a, unsigned b) {
    while (true) {
        a = uf_find(p, a);
        b = uf_find(p, b);
        if (a == b) return;
        if (a < b) { unsigned t = a; a = b; b = t; }   // a = max root
        unsigned old = atomicCAS(&p[b], b, a);
        if (old == b) return;
        b = old;
    }
}

// ---- LDS union-find (same invariants, shared-memory atomics) ----
__device__ __forceinline__ unsigned lfind(unsigned* p, unsigned i) {
    while (true) {
        unsigned pi = ((volatile unsigned*)p)[i];
        if (pi == i) return i;
        unsigned gp = ((volatile unsigned*)p)[pi];
        if (gp != pi) ((volatile unsigned*)p)[i] = gp;
        i = pi;
    }
}
__device__ void lunion(unsigned* p, unsigned a, unsigned b) {
    while (true) {
        a = lfind(p, a);
        b = lfind(p, b);
        if (a == b) return;
        if (a < b) { unsigned t = a; a = b; b = t; }
        unsigned old = atomicCAS(&p[b], b, a);
        if (old == b) return;
        b = old;
    }
}

__global__ void k_init(unsigned* mmkey) {
    int t = threadIdx.x;
    if (t < 3 * BB) mmkey[t * 2] = INV;  // min-key sentinel (max-key=0 from memset)
}

// channel mean + per-sample min/max
__global__ void k_cmean(const float* __restrict__ x0, const float* __restrict__ x1,
                        const float* __restrict__ x2, float* __restrict__ cmean,
                        unsigned* __restrict__ mmkey) {
    int z = blockIdx.z, b = blockIdx.y, t = threadIdx.x;
    const float* x = (z == 0) ? x0 : (z == 1) ? x1 : x2;
    int hw4 = (blockIdx.x * blockDim.x + t) * 4;
    size_t base = (size_t)b * CC * HWs + hw4;
    float4 s = make_float4(0.f, 0.f, 0.f, 0.f);
#pragma unroll 4
    for (int c = 0; c < CC; c++) {
        float4 v = *reinterpret_cast<const float4*>(x + base + (size_t)c * HWs);
        s.x += v.x; s.y += v.y; s.z += v.z; s.w += v.w;
    }
    const float inv = 1.f / 64.f;   // /64 is exact pow2, identical to mean
    s.x *= inv; s.y *= inv; s.z *= inv; s.w *= inv;
    *reinterpret_cast<float4*>(cmean + (size_t)z * NN + (size_t)b * HWs + hw4) = s;

    float mn = fminf(fminf(s.x, s.y), fminf(s.z, s.w));
    float mx = fmaxf(fmaxf(s.x, s.y), fmaxf(s.z, s.w));
    for (int o = 32; o; o >>= 1) {
        mn = fminf(mn, __shfl_down(mn, o));
        mx = fmaxf(mx, __shfl_down(mx, o));
    }
    __shared__ float smn[4], smx[4];
    int wid = t >> 6, lane = t & 63;
    if (lane == 0) { smn[wid] = mn; smx[wid] = mx; }
    __syncthreads();
    if (t == 0) {
        mn = fminf(fminf(smn[0], smn[1]), fminf(smn[2], smn[3]));
        mx = fmaxf(fmaxf(smx[0], smx[1]), fmaxf(smx[2], smx[3]));
        atomicMin(&mmkey[(z * BB + b) * 2 + 0], f2key(mn));
        atomicMax(&mmkey[(z * BB + b) * 2 + 1], f2key(mx));
    }
}

// fused: normalize -> mask -> LOCAL run-based CCL over a [16b x 8h x 32w] tile.
// Each tile row (b,h) is one 32-bit ballot word; every voxel derives its w-run
// root DIRECTLY from the bitmask (zero atomics, zero chains). h/b edges are
// unioned once per overlapping run pair (leader bits of ov & ~(ov<<1)) —
// ~1k short-path LDS unions per tile instead of ~10k contended ones.
// Local li = lb*256 + lh*32 + lw is order-isomorphic to the global index, so
// run root = run max and union-by-max root = component max, preserving the
// global "root = max linear index" invariant.
__global__ void __launch_bounds__(256) k_mask_ccl(const float* __restrict__ cmean,
                                                  const unsigned* __restrict__ mmkey,
                                                  unsigned* __restrict__ parent_all) {
    int z = blockIdx.z;
    int h0 = blockIdx.y * TILE_H;
    int w0 = blockIdx.x * TILE_W;
    int t = threadIdx.x;
    int lane = t & 63;
    __shared__ unsigned sp[TVOX];
    __shared__ unsigned rowmask[NROWS];
    __shared__ float smn[BB], smx[BB];
    if (t < BB) {
        smn[t] = key2f(mmkey[(z * BB + t) * 2 + 0]);
        smx[t] = key2f(mmkey[(z * BB + t) * 2 + 1]);
    }
    __syncthreads();
#pragma unroll
    for (int ph = 0; ph < TVOX / 256; ph++) {
        int li = ph * 256 + t;
        int lb = li >> 8, lh = (li >> 5) & 7, lw = li & 31;
        unsigned gi = lb * HWs + (h0 + lh) * WW + (w0 + lw);
        float c = cmean[(size_t)z * NN + gi];
        bool mkd = (c - smn[lb]) / (smx[lb] - smn[lb]) >= 0.4f;
        unsigned long long bal = __ballot(mkd);
        unsigned m = (lane < 32) ? (unsigned)bal : (unsigned)(bal >> 32);
        int row = li >> 5;
        if ((lane & 31) == 0) rowmask[row] = m;
        unsigned v = INV;
        if (mkd) {
            int j = __ffsll(~((unsigned long long)m >> lw)) - 1;  // trailing-ones >=1
            v = (unsigned)((row << 5) + lw + j - 1);              // run root (run max)
        }
        sp[li] = v;
    }
    __syncthreads();
#pragma unroll
    for (int ph = 0; ph < TVOX / 256; ph++) {
        int li = ph * 256 + t;
        int row = li >> 5, lw = li & 31;
        unsigned m = rowmask[row];
        if (!((m >> lw) & 1)) continue;
        int lh = row & 7;
        if (lh < TILE_H - 1) {                       // h-edge, row -> row+1
            unsigned m2 = rowmask[row + 1];
            unsigned ov = m & m2;
            bool leader = ((ov >> lw) & 1) && (lw == 0 || !((ov >> (lw - 1)) & 1));
            if (leader) {
                int j2 = __ffsll(~((unsigned long long)m2 >> lw)) - 1;
                lunion(sp, sp[li], (unsigned)(((row + 1) << 5) + lw + j2 - 1));
            }
        }
        if (row < NROWS - 8) {                       // b-edge, row -> row+8
            unsigned m2 = rowmask[row + 8];
            unsigned ov = m & m2;
            bool leader = ((ov >> lw) & 1) && (lw == 0 || !((ov >> (lw - 1)) & 1));
            if (leader) {
                int j2 = __ffsll(~((unsigned long long)m2 >> lw)) - 1;
                lunion(sp, sp[li], (unsigned)(((row + 8) << 5) + lw + j2 - 1));
            }
        }
    }
    __syncthreads();
#pragma unroll
    for (int ph = 0; ph < TVOX / 256; ph++) {
        int li = ph * 256 + t;
        int lb = li >> 8, lh = (li >> 5) & 7, lw = li & 31;
        unsigned gi = lb * HWs + (h0 + lh) * WW + (w0 + lw);
        unsigned v = sp[li];
        if (v != INV) {
            unsigned r = v;
            while (sp[r] != r) r = sp[r];           // quiescent after barrier
            int rb = r >> 8, rh = (r >> 5) & 7, rw = r & 31;
            v = rb * HWs + (h0 + rh) * WW + (w0 + rw);
        }
        parent_all[(size_t)z * NN + gi] = v;
    }
}

// global unions only across tile boundaries, with run-leader dedup
__global__ void k_merge_bnd(unsigned* __restrict__ parent_all) {
    int z = blockIdx.y;
    unsigned* p = parent_all + (size_t)z * NN;
    int e = blockIdx.x * 256 + threadIdx.x;
    if (e >= NEDGE) return;
    unsigned i, j;
    bool lead = true;
    if (e < NWEDGE) {
        int k = e % 7, rest = e / 7;           // rest = b*128 + h
        int h = rest & (HH - 1), b = rest >> 7;
        int w = k * TILE_W + (TILE_W - 1);
        i = b * HWs + h * WW + w; j = i + 1;
        if ((h & (TILE_H - 1)) != 0)           // prev-h pair in same tiles?
            if (p[i - WW] != INV && p[j - WW] != INV) lead = false;
    } else {
        int e2 = e - NWEDGE;
        int k = e2 % 15, rest = e2 / 15;       // rest = b*256 + w
        int w = rest & (WW - 1), b = rest >> 8;
        int h = k * TILE_H + (TILE_H - 1);
        i = b * HWs + h * WW + w; j = i + WW;
        if ((w & (TILE_W - 1)) != 0)
            if (p[i - 1] != INV && p[j - 1] != INV) lead = false;
    }
    if (lead && p[i] != INV && p[j] != INV) uf_union(p, i, j);
}

__global__ void k_compress(unsigned* __restrict__ parent_all, unsigned* __restrict__ dense_all,
                           unsigned* __restrict__ rootlab, unsigned* __restrict__ Kc) {
    int z = blockIdx.y;
    unsigned* p = parent_all + (size_t)z * NN;
    unsigned i = blockIdx.x * 256 + threadIdx.x;
    if (p[i] == INV) return;
    unsigned r = uf_find(p, i);
    p[i] = r;
    if (r == i) {
        unsigned id = atomicAdd(&Kc[z], 1u);
        if (id >= KMAX) id = KMAX - 1;   // never expected (components ~ tens)
        dense_all[(size_t)z * NN + i] = id;
        rootlab[z * KMAX + id] = i;
    }
}

// per-slice per-component counts, wave-aggregated atomics
__global__ void k_count(const unsigned* __restrict__ parent_all,
                        const unsigned* __restrict__ dense_all, int* __restrict__ counts) {
    int z = blockIdx.y;
    const unsigned* p = parent_all + (size_t)z * NN;
    const unsigned* d = dense_all + (size_t)z * NN;
    int i = blockIdx.x * 256 + threadIdx.x;
    int b = i >> 15;   // uniform across the wave (64 | HWs)
    unsigned pi = p[i];
    bool valid = (pi != INV);
    int id = valid ? (int)d[pi] : -1;
    int lane = threadIdx.x & 63;
    int* crow = counts + ((size_t)z * BB + b) * KMAX;
    unsigned long long rem = __ballot(valid);
    while (rem) {
        int leader = __ffsll(rem) - 1;
        int lid = __shfl(id, leader);
        unsigned long long m = __ballot(valid && id == lid) & rem;
        if (lane == leader) atomicAdd(&crow[lid], (int)__popcll(m));
        rem &= ~m;
    }
}

// per-slice argmax: max count, tie -> smallest root label (== reference argmax semantics)
__global__ void k_best(const int* __restrict__ counts, const unsigned* __restrict__ rootlab,
                       const unsigned* __restrict__ Kc, unsigned* __restrict__ best) {
    int z = blockIdx.y, b = blockIdx.x, t = threadIdx.x;
    const int* crow = counts + ((size_t)z * BB + b) * KMAX;
    const unsigned* rl = rootlab + z * KMAX;
    unsigned K = Kc[z]; if (K > KMAX) K = KMAX;
    int bc = -1; unsigned brl = INV; int bj = 0;
    for (unsigned j = t; j < K; j += blockDim.x) {
        int c = crow[j]; unsigned r = rl[j];
        if (c > bc || (c == bc && r < brl)) { bc = c; brl = r; bj = (int)j; }
    }
    __shared__ int sc[256]; __shared__ unsigned sr[256]; __shared__ int sj[256];
    sc[t] = bc; sr[t] = brl; sj[t] = bj;
    __syncthreads();
    for (int o = 128; o; o >>= 1) {
        if (t < o) {
            int c2 = sc[t + o]; unsigned r2 = sr[t + o];
            if (c2 > sc[t] || (c2 == sc[t] && r2 < sr[t])) { sc[t] = c2; sr[t] = r2; sj[t] = sj[t + o]; }
        }
        __syncthreads();
    }
    if (t == 0) best[z * BB + b] = (unsigned)sj[0];
}

// masked normalized output + integer centroid sums
__global__ void k_result(const float* __restrict__ cmean, const unsigned* __restrict__ parent_all,
                         const unsigned* __restrict__ dense_all, const unsigned* __restrict__ mmkey,
                         const unsigned* __restrict__ best, float* __restrict__ out,
                         int* __restrict__ cent) {
    int z = blockIdx.y;
    int i = blockIdx.x * 256 + threadIdx.x;
    int b = i >> 15;
    const unsigned* p = parent_all + (size_t)z * NN;
    unsigned pi = p[i];
    bool big = false;
    if (pi != INV) big = (dense_all[(size_t)z * NN + pi] == best[z * BB + b]);
    float mn = key2f(mmkey[(z * BB + b) * 2 + 0]);
    float mx = key2f(mmkey[(z * BB + b) * 2 + 1]);
    float c = cmean[(size_t)z * NN + i];
    float v = (c - mn) / (mx - mn);
    out[32 + (size_t)z * NN + i] = big ? v : 0.f;

    int c1 = big ? 1 : 0;
    int ch = big ? ((i >> 8) & (HH - 1)) : 0;
    int cw = big ? (i & (WW - 1)) : 0;
    for (int o = 32; o; o >>= 1) {
        c1 += __shfl_down(c1, o); ch += __shfl_down(ch, o); cw += __shfl_down(cw, o);
    }
    __shared__ int s0[4], s1[4], s2[4];
    int wid = threadIdx.x >> 6, lane = threadIdx.x & 63;
    if (lane == 0) { s0[wid] = c1; s1[wid] = ch; s2[wid] = cw; }
    __syncthreads();
    if (threadIdx.x == 0) {
        c1 = s0[0] + s0[1] + s0[2] + s0[3];
        ch = s1[0] + s1[1] + s1[2] + s1[3];
        cw = s2[0] + s2[1] + s2[2] + s2[3];
        int* ct = cent + (z * BB + b) * 3;
        atomicAdd(&ct[0], c1); atomicAdd(&ct[1], ch); atomicAdd(&ct[2], cw);
    }
}

__global__ void k_final(const int* __restrict__ cent, float* __restrict__ out) {
    int b = threadIdx.x;
    if (b >= BB) return;
    const float PI = (float)M_PI;  // f32(np.pi)
    float th[3], ph[3];
    for (int z = 0; z < 3; z++) {
        const int* ct = cent + (z * BB + b) * 3;
        float cnt = (float)ct[0];
        float hm = (float)ct[1] / cnt;   // integer sums exact in f32 (< 2^24)
        float wm = (float)ct[2] / cnt;
        ph[z] = (0.5f - hm / (float)HH) * PI;
        th[z] = (wm / (float)WW - 0.5f) * 2.0f * PI;
    }
    auto dist = [PI](float t1, float p1, float t2, float p2) {
        float cosd = sinf(t1) * sinf(t2) + cosf(t1) * cosf(t2) * cosf(p1 - p2);
        float d = acosf(cosd);
        if (isnan(d)) d = 0.f;           // jnp.nan_to_num semantics
        return d / PI;
    };
    out[b]      = dist(th[0], ph[0], th[1], ph[1]);
    out[BB + b] = dist(th[1], ph[1], th[2], ph[2]);
}

extern "C" void kernel_launch(void* const* d_in, const int* in_sizes, int n_in,
                              void* d_out, int out_size, void* d_ws, size_t ws_size,
                              hipStream_t stream) {
    const float* x0 = (const float*)d_in[0];
    const float* x1 = (const float*)d_in[1];
    const float* x2 = (const float*)d_in[2];
    float* out = (float*)d_out;
    char* ws = (char*)d_ws;
    float*    cmean   = (float*)(ws + OFF_CMEAN);
    unsigned* parent  = (unsigned*)(ws + OFF_PARENT);
    unsigned* dense   = (unsigned*)(ws + OFF_DENSE);
    int*      counts  = (int*)(ws + OFF_COUNTS);
    unsigned* rootlab = (unsigned*)(ws + OFF_ROOTLAB);
    unsigned* mmkey   = (unsigned*)(ws + OFF_MMKEY);
    unsigned* Kc      = (unsigned*)(ws + OFF_K);
    unsigned* best    = (unsigned*)(ws + OFF_BEST);
    int*      cent    = (int*)(ws + OFF_CENT);

    hipMemsetAsync(ws + OFF_COUNTS, 0, OFF_END - OFF_COUNTS, stream);
    hipLaunchKernelGGL(k_init, dim3(1), dim3(64), 0, stream, mmkey);
    hipLaunchKernelGGL(k_cmean, dim3(HWs / 1024, BB, 3), dim3(256), 0, stream,
                       x0, x1, x2, cmean, mmkey);
    hipLaunchKernelGGL(k_mask_ccl, dim3(WW / TILE_W, HH / TILE_H, 3), dim3(256), 0, stream,
                       cmean, mmkey, parent);
    hipLaunchKernelGGL(k_merge_bnd, dim3((NEDGE + 255) / 256, 3), dim3(256), 0, stream, parent);
    hipLaunchKernelGGL(k_compress, dim3(NN / 256, 3), dim3(256), 0, stream,
                       parent, dense, rootlab, Kc);
    hipLaunchKernelGGL(k_count, dim3(NN / 256, 3), dim3(256), 0, stream, parent, dense, counts);
    hipLaunchKernelGGL(k_best, dim3(BB, 3), dim3(256), 0, stream, counts, rootlab, Kc, best);
    hipLaunchKernelGGL(k_result, dim3(NN / 256, 3), dim3(256), 0, stream,
                       cmean, parent, dense, mmkey, best, out, cent);
    hipLaunchKernelGGL(k_final, dim3(1), dim3(64), 0, stream, cent, out);
}

// Round 4
// 647.338 us; speedup vs baseline: 3.6167x; 1.0335x over previous
//
#include <hip/hip_runtime.h>
#include <math.h>

#define BB 16
#define CC 64
#define HH 128
#define WW 256
#define HWs 32768      // HH*WW
#define NN 524288      // BB*HH*WW
#define KMAX 8192
#define INV 0xFFFFFFFFu

// tile: full batch depth x 8h x 32w = 4096 voxels
#define TILE_H 8
#define TILE_W 32
#define TVOX 4096
#define NROWS 128      // BB * TILE_H rows of 32 w-bits
#define NWEDGE 14336   // 7 internal w-boundaries * 16b * 128h
#define NHEDGE 61440   // 15 internal h-boundaries * 16b * 256w
#define NEDGE  75776

// ---- workspace layout (bytes) ----
#define OFF_CMEAN   0                                  // f32 [3][NN]
#define OFF_PARENT  (OFF_CMEAN  + 3*NN*4)              // u32 [3][NN]
#define OFF_DENSE   (OFF_PARENT + 3*NN*4)              // u32 [3][NN]
#define OFF_COUNTS  (OFF_DENSE  + 3*NN*4)              // i32 [3][BB][KMAX]
#define OFF_ROOTLAB (OFF_COUNTS + 3*BB*KMAX*4)         // u32 [3][KMAX]
#define OFF_MMKEY   (OFF_ROOTLAB+ 3*KMAX*4)            // u32 [3][BB][2]  (~minkey,maxkey) both atomicMax, init 0
#define OFF_K       (OFF_MMKEY  + 3*BB*2*4)            // u32 [3] (+pad)
#define OFF_BEST    (OFF_K      + 16)                  // u32 [3][BB]
#define OFF_CENT    (OFF_BEST   + 3*BB*4)              // i32 [3][BB][3]
#define OFF_END     (OFF_CENT   + 3*BB*3*4)

// monotone float<->uint key (order-preserving incl. negatives)
__device__ __forceinline__ unsigned f2key(float f) {
    unsigned u = __float_as_uint(f);
    return (u & 0x80000000u) ? ~u : (u | 0x80000000u);
}
__device__ __forceinline__ float key2f(unsigned k) {
    unsigned u = (k & 0x80000000u) ? (k ^ 0x80000000u) : ~k;
    return __uint_as_float(u);
}

// ---- union-find, links always point to LARGER index => root = max linear idx ----
__device__ unsigned uf_find(unsigned* p, unsigned i) {
    while (true) {
        unsigned pi = ((volatile unsigned*)p)[i];
        if (pi == i) return i;
        unsigned gp = ((volatile unsigned*)p)[pi];
        if (gp != pi) ((volatile unsigned*)p)[i] = gp;  // path halving (monotone, safe)
        i = pi;
    }
}
__device__ void uf_union(unsigned* p, unsigned a, unsigned b) {
    while (true) {
        a = uf_find(p, a);
        b = uf_find(p, b);
        if (a == b) return;
        if (a < b) { unsigned t = a; a = b; b = t; }   // a = max root
        unsigned old = atomicCAS(&p[b], b, a);
        if (old == b) return;
        b = old;
    }
}

// ---- LDS union-find (same invariants, shared-memory atomics) ----
__device__ __forceinline__ unsigned lfind(unsigned* p, unsigned i) {
    while (true) {
        unsigned pi = ((volatile unsigned*)p)[i];
        if (pi == i) return i;
        unsigned gp = ((volatile unsigned*)p)[pi];
        if (gp != pi) ((volatile unsigned*)p)[i] = gp;
        i = pi;
    }
}
__device__ void lunion(unsigned* p, unsigned a, unsigned b) {
    while (true) {
        a = lfind(p, a);
        b = lfind(p, b);
        if (a == b) return;
        if (a < b) { unsigned t = a; a = b; b = t; }
        unsigned old = atomicCAS(&p[b], b, a);
        if (old == b) return;
        b = old;
    }
}

// channel mean + per-sample min/max; fully unrolled channel loop with 4
// independent accumulators so the compiler can cluster many dwordx4 loads
// (MLP against ~900cy HBM latency). mmkey: slot0 = max(~key) (== ~min),
// slot1 = max(key); both init 0 by the workspace memset (no k_init launch).
__global__ void k_cmean(const float* __restrict__ x0, const float* __restrict__ x1,
                        const float* __restrict__ x2, float* __restrict__ cmean,
                        unsigned* __restrict__ mmkey) {
    int z = blockIdx.z, b = blockIdx.y, t = threadIdx.x;
    const float* x = (z == 0) ? x0 : (z == 1) ? x1 : x2;
    int hw4 = (blockIdx.x * blockDim.x + t) * 4;
    const float* px = x + (size_t)b * CC * HWs + hw4;
    float4 s0 = make_float4(0.f, 0.f, 0.f, 0.f);
    float4 s1 = s0, s2 = s0, s3 = s0;
#pragma unroll
    for (int c = 0; c < CC; c += 4) {
        float4 v0 = *reinterpret_cast<const float4*>(px + (size_t)(c + 0) * HWs);
        float4 v1 = *reinterpret_cast<const float4*>(px + (size_t)(c + 1) * HWs);
        float4 v2 = *reinterpret_cast<const float4*>(px + (size_t)(c + 2) * HWs);
        float4 v3 = *reinterpret_cast<const float4*>(px + (size_t)(c + 3) * HWs);
        s0.x += v0.x; s0.y += v0.y; s0.z += v0.z; s0.w += v0.w;
        s1.x += v1.x; s1.y += v1.y; s1.z += v1.z; s1.w += v1.w;
        s2.x += v2.x; s2.y += v2.y; s2.z += v2.z; s2.w += v2.w;
        s3.x += v3.x; s3.y += v3.y; s3.z += v3.z; s3.w += v3.w;
    }
    float4 s;
    s.x = (s0.x + s1.x) + (s2.x + s3.x);
    s.y = (s0.y + s1.y) + (s2.y + s3.y);
    s.z = (s0.z + s1.z) + (s2.z + s3.z);
    s.w = (s0.w + s1.w) + (s2.w + s3.w);
    const float inv = 1.f / 64.f;   // /64 is exact pow2, identical to mean
    s.x *= inv; s.y *= inv; s.z *= inv; s.w *= inv;
    *reinterpret_cast<float4*>(cmean + (size_t)z * NN + (size_t)b * HWs + hw4) = s;

    float mn = fminf(fminf(s.x, s.y), fminf(s.z, s.w));
    float mx = fmaxf(fmaxf(s.x, s.y), fmaxf(s.z, s.w));
    for (int o = 32; o; o >>= 1) {
        mn = fminf(mn, __shfl_down(mn, o));
        mx = fmaxf(mx, __shfl_down(mx, o));
    }
    __shared__ float smn[4], smx[4];
    int wid = t >> 6, lane = t & 63;
    if (lane == 0) { smn[wid] = mn; smx[wid] = mx; }
    __syncthreads();
    if (t == 0) {
        mn = fminf(fminf(smn[0], smn[1]), fminf(smn[2], smn[3]));
        mx = fmaxf(fmaxf(smx[0], smx[1]), fmaxf(smx[2], smx[3]));
        atomicMax(&mmkey[(z * BB + b) * 2 + 0], ~f2key(mn));
        atomicMax(&mmkey[(z * BB + b) * 2 + 1], f2key(mx));
    }
}

// fused: normalize -> mask -> LOCAL run-based CCL over a [16b x 8h x 32w] tile.
// Each tile row (b,h) is one 32-bit ballot word; every voxel derives its w-run
// root DIRECTLY from the bitmask (zero atomics, zero chains). h/b edges are
// unioned once per overlapping run pair. After unions the static tree is
// flattened by race-safe pointer jumping, so the final root lookup is O(1).
__global__ void __launch_bounds__(256) k_mask_ccl(const float* __restrict__ cmean,
                                                  const unsigned* __restrict__ mmkey,
                                                  unsigned* __restrict__ parent_all) {
    int z = blockIdx.z;
    int h0 = blockIdx.y * TILE_H;
    int w0 = blockIdx.x * TILE_W;
    int t = threadIdx.x;
    int lane = t & 63;
    __shared__ unsigned sp[TVOX];
    __shared__ unsigned rowmask[NROWS];
    __shared__ float smn[BB], smx[BB];
    if (t < BB) {
        smn[t] = key2f(~mmkey[(z * BB + t) * 2 + 0]);
        smx[t] = key2f(mmkey[(z * BB + t) * 2 + 1]);
    }
    __syncthreads();
#pragma unroll
    for (int ph = 0; ph < TVOX / 256; ph++) {
        int li = ph * 256 + t;
        int lb = li >> 8, lh = (li >> 5) & 7, lw = li & 31;
        unsigned gi = lb * HWs + (h0 + lh) * WW + (w0 + lw);
        float c = cmean[(size_t)z * NN + gi];
        bool mkd = (c - smn[lb]) / (smx[lb] - smn[lb]) >= 0.4f;
        unsigned long long bal = __ballot(mkd);
        unsigned m = (lane < 32) ? (unsigned)bal : (unsigned)(bal >> 32);
        int row = li >> 5;
        if ((lane & 31) == 0) rowmask[row] = m;
        unsigned v = INV;
        if (mkd) {
            int j = __ffsll(~((unsigned long long)m >> lw)) - 1;  // trailing-ones >=1
            v = (unsigned)((row << 5) + lw + j - 1);              // run root (run max)
        }
        sp[li] = v;
    }
    __syncthreads();
#pragma unroll
    for (int ph = 0; ph < TVOX / 256; ph++) {
        int li = ph * 256 + t;
        int row = li >> 5, lw = li & 31;
        unsigned m = rowmask[row];
        if (!((m >> lw) & 1)) continue;
        int lh = row & 7;
        if (lh < TILE_H - 1) {                       // h-edge, row -> row+1
            unsigned m2 = rowmask[row + 1];
            unsigned ov = m & m2;
            bool leader = ((ov >> lw) & 1) && (lw == 0 || !((ov >> (lw - 1)) & 1));
            if (leader) {
                int j2 = __ffsll(~((unsigned long long)m2 >> lw)) - 1;
                lunion(sp, sp[li], (unsigned)(((row + 1) << 5) + lw + j2 - 1));
            }
        }
        if (row < NROWS - 8) {                       // b-edge, row -> row+8
            unsigned m2 = rowmask[row + 8];
            unsigned ov = m & m2;
            bool leader = ((ov >> lw) & 1) && (lw == 0 || !((ov >> (lw - 1)) & 1));
            if (leader) {
                int j2 = __ffsll(~((unsigned long long)m2 >> lw)) - 1;
                lunion(sp, sp[li], (unsigned)(((row + 8) << 5) + lw + j2 - 1));
            }
        }
    }
    __syncthreads();
    // pointer-jump flatten: tree is static now; concurrent sp[li]=sp[sp[li]]
    // only moves entries to (valid) ancestors, monotone toward the root.
#pragma unroll
    for (int it = 0; it < 4; it++) {
#pragma unroll
        for (int ph = 0; ph < TVOX / 256; ph++) {
            int li = ph * 256 + t;
            unsigned v = sp[li];
            if (v != INV) {
                unsigned w = sp[v];
                if (w != v) sp[li] = w;
            }
        }
    }
    __syncthreads();
#pragma unroll
    for (int ph = 0; ph < TVOX / 256; ph++) {
        int li = ph * 256 + t;
        int lb = li >> 8, lh = (li >> 5) & 7, lw = li & 31;
        unsigned gi = lb * HWs + (h0 + lh) * WW + (w0 + lw);
        unsigned v = sp[li];
        if (v != INV) {
            unsigned r = v;
            while (sp[r] != r) r = sp[r];           // short after flatten
            int rb = r >> 8, rh = (r >> 5) & 7, rw = r & 31;
            v = rb * HWs + (h0 + rh) * WW + (w0 + rw);
        }
        parent_all[(size_t)z * NN + gi] = v;
    }
}

// global unions only across tile boundaries, with run-leader dedup
__global__ void k_merge_bnd(unsigned* __restrict__ parent_all) {
    int z = blockIdx.y;
    unsigned* p = parent_all + (size_t)z * NN;
    int e = blockIdx.x * 256 + threadIdx.x;
    if (e >= NEDGE) return;
    unsigned i, j;
    bool lead = true;
    if (e < NWEDGE) {
        int k = e % 7, rest = e / 7;           // rest = b*128 + h
        int h = rest & (HH - 1), b = rest >> 7;
        int w = k * TILE_W + (TILE_W - 1);
        i = b * HWs + h * WW + w; j = i + 1;
        if ((h & (TILE_H - 1)) != 0)           // prev-h pair in same tiles?
            if (p[i - WW] != INV && p[j - WW] != INV) lead = false;
    } else {
        int e2 = e - NWEDGE;
        int k = e2 % 15, rest = e2 / 15;       // rest = b*256 + w
        int w = rest & (WW - 1), b = rest >> 8;
        int h = k * TILE_H + (TILE_H - 1);
        i = b * HWs + h * WW + w; j = i + WW;
        if ((w & (TILE_W - 1)) != 0)
            if (p[i - 1] != INV && p[j - 1] != INV) lead = false;
    }
    if (lead && p[i] != INV && p[j] != INV) uf_union(p, i, j);
}

__global__ void k_compress(unsigned* __restrict__ parent_all, unsigned* __restrict__ dense_all,
                           unsigned* __restrict__ rootlab, unsigned* __restrict__ Kc) {
    int z = blockIdx.y;
    unsigned* p = parent_all + (size_t)z * NN;
    unsigned i = blockIdx.x * 256 + threadIdx.x;
    if (p[i] == INV) return;
    unsigned r = uf_find(p, i);
    p[i] = r;
    if (r == i) {
        unsigned id = atomicAdd(&Kc[z], 1u);
        if (id >= KMAX) id = KMAX - 1;   // never expected (components ~ tens)
        dense_all[(size_t)z * NN + i] = id;
        rootlab[z * KMAX + id] = i;
    }
}

// per-slice per-component counts, wave-aggregated atomics
__global__ void k_count(const unsigned* __restrict__ parent_all,
                        const unsigned* __restrict__ dense_all, int* __restrict__ counts) {
    int z = blockIdx.y;
    const unsigned* p = parent_all + (size_t)z * NN;
    const unsigned* d = dense_all + (size_t)z * NN;
    int i = blockIdx.x * 256 + threadIdx.x;
    int b = i >> 15;   // uniform across the wave (64 | HWs)
    unsigned pi = p[i];
    bool valid = (pi != INV);
    int id = valid ? (int)d[pi] : -1;
    int lane = threadIdx.x & 63;
    int* crow = counts + ((size_t)z * BB + b) * KMAX;
    unsigned long long rem = __ballot(valid);
    while (rem) {
        int leader = __ffsll(rem) - 1;
        int lid = __shfl(id, leader);
        unsigned long long m = __ballot(valid && id == lid) & rem;
        if (lane == leader) atomicAdd(&crow[lid], (int)__popcll(m));
        rem &= ~m;
    }
}

// per-slice argmax: max count, tie -> smallest root label (== reference argmax semantics)
__global__ void k_best(const int* __restrict__ counts, const unsigned* __restrict__ rootlab,
                       const unsigned* __restrict__ Kc, unsigned* __restrict__ best) {
    int z = blockIdx.y, b = blockIdx.x, t = threadIdx.x;
    const int* crow = counts + ((size_t)z * BB + b) * KMAX;
    const unsigned* rl = rootlab + z * KMAX;
    unsigned K = Kc[z]; if (K > KMAX) K = KMAX;
    int bc = -1; unsigned brl = INV; int bj = 0;
    for (unsigned j = t; j < K; j += blockDim.x) {
        int c = crow[j]; unsigned r = rl[j];
        if (c > bc || (c == bc && r < brl)) { bc = c; brl = r; bj = (int)j; }
    }
    __shared__ int sc[256]; __shared__ unsigned sr[256]; __shared__ int sj[256];
    sc[t] = bc; sr[t] = brl; sj[t] = bj;
    __syncthreads();
    for (int o = 128; o; o >>= 1) {
        if (t < o) {
            int c2 = sc[t + o]; unsigned r2 = sr[t + o];
            if (c2 > sc[t] || (c2 == sc[t] && r2 < sr[t])) { sc[t] = c2; sr[t] = r2; sj[t] = sj[t + o]; }
        }
        __syncthreads();
    }
    if (t == 0) best[z * BB + b] = (unsigned)sj[0];
}

// masked normalized output + integer centroid sums
__global__ void k_result(const float* __restrict__ cmean, const unsigned* __restrict__ parent_all,
                         const unsigned* __restrict__ dense_all, const unsigned* __restrict__ mmkey,
                         const unsigned* __restrict__ best, float* __restrict__ out,
                         int* __restrict__ cent) {
    int z = blockIdx.y;
    int i = blockIdx.x * 256 + threadIdx.x;
    int b = i >> 15;
    const unsigned* p = parent_all + (size_t)z * NN;
    unsigned pi = p[i];
    bool big = false;
    if (pi != INV) big = (dense_all[(size_t)z * NN + pi] == best[z * BB + b]);
    float mn = key2f(~mmkey[(z * BB + b) * 2 + 0]);
    float mx = key2f(mmkey[(z * BB + b) * 2 + 1]);
    float c = cmean[(size_t)z * NN + i];
    float v = (c - mn) / (mx - mn);
    out[32 + (size_t)z * NN + i] = big ? v : 0.f;

    int c1 = big ? 1 : 0;
    int ch = big ? ((i >> 8) & (HH - 1)) : 0;
    int cw = big ? (i & (WW - 1)) : 0;
    for (int o = 32; o; o >>= 1) {
        c1 += __shfl_down(c1, o); ch += __shfl_down(ch, o); cw += __shfl_down(cw, o);
    }
    __shared__ int s0[4], s1[4], s2[4];
    int wid = threadIdx.x >> 6, lane = threadIdx.x & 63;
    if (lane == 0) { s0[wid] = c1; s1[wid] = ch; s2[wid] = cw; }
    __syncthreads();
    if (threadIdx.x == 0) {
        c1 = s0[0] + s0[1] + s0[2] + s0[3];
        ch = s1[0] + s1[1] + s1[2] + s1[3];
        cw = s2[0] + s2[1] + s2[2] + s2[3];
        int* ct = cent + (z * BB + b) * 3;
        atomicAdd(&ct[0], c1); atomicAdd(&ct[1], ch); atomicAdd(&ct[2], cw);
    }
}

__global__ void k_final(const int* __restrict__ cent, float* __restrict__ out) {
    int b = threadIdx.x;
    if (b >= BB) return;
    const float PI = (float)M_PI;  // f32(np.pi)
    float th[3], ph[3];
    for (int z = 0; z < 3; z++) {
        const int* ct = cent + (z * BB + b) * 3;
        float cnt = (float)ct[0];
        float hm = (float)ct[1] / cnt;   // integer sums exact in f32 (< 2^24)
        float wm = (float)ct[2] / cnt;
        ph[z] = (0.5f - hm / (float)HH) * PI;
        th[z] = (wm / (float)WW - 0.5f) * 2.0f * PI;
    }
    auto dist = [PI](float t1, float p1, float t2, float p2) {
        float cosd = sinf(t1) * sinf(t2) + cosf(t1) * cosf(t2) * cosf(p1 - p2);
        float d = acosf(cosd);
        if (isnan(d)) d = 0.f;           // jnp.nan_to_num semantics
        return d / PI;
    };
    out[b]      = dist(th[0], ph[0], th[1], ph[1]);
    out[BB + b] = dist(th[1], ph[1], th[2], ph[2]);
}

extern "C" void kernel_launch(void* const* d_in, const int* in_sizes, int n_in,
                              void* d_out, int out_size, void* d_ws, size_t ws_size,
                              hipStream_t stream) {
    const float* x0 = (const float*)d_in[0];
    const float* x1 = (const float*)d_in[1];
    const float* x2 = (const float*)d_in[2];
    float* out = (float*)d_out;
    char* ws = (char*)d_ws;
    float*    cmean   = (float*)(ws + OFF_CMEAN);
    unsigned* parent  = (unsigned*)(ws + OFF_PARENT);
    unsigned* dense   = (unsigned*)(ws + OFF_DENSE);
    int*      counts  = (int*)(ws + OFF_COUNTS);
    unsigned* rootlab = (unsigned*)(ws + OFF_ROOTLAB);
    unsigned* mmkey   = (unsigned*)(ws + OFF_MMKEY);
    unsigned* Kc      = (unsigned*)(ws + OFF_K);
    unsigned* best    = (unsigned*)(ws + OFF_BEST);
    int*      cent    = (int*)(ws + OFF_CENT);

    hipMemsetAsync(ws + OFF_COUNTS, 0, OFF_END - OFF_COUNTS, stream);
    hipLaunchKernelGGL(k_cmean, dim3(HWs / 1024, BB, 3), dim3(256), 0, stream,
                       x0, x1, x2, cmean, mmkey);
    hipLaunchKernelGGL(k_mask_ccl, dim3(WW / TILE_W, HH / TILE_H, 3), dim3(256), 0, stream,
                       cmean, mmkey, parent);
    hipLaunchKernelGGL(k_merge_bnd, dim3((NEDGE + 255) / 256, 3), dim3(256), 0, stream, parent);
    hipLaunchKernelGGL(k_compress, dim3(NN / 256, 3), dim3(256), 0, stream,
                       parent, dense, rootlab, Kc);
    hipLaunchKernelGGL(k_count, dim3(NN / 256, 3), dim3(256), 0, stream, parent, dense, counts);
    hipLaunchKernelGGL(k_best, dim3(BB, 3), dim3(256), 0, stream, counts, rootlab, Kc, best);
    hipLaunchKernelGGL(k_result, dim3(NN / 256, 3), dim3(256), 0, stream,
                       cmean, parent, dense, mmkey, best, out, cent);
    hipLaunchKernelGGL(k_final, dim3(1), dim3(64), 0, stream, cent, out);
}

// Round 5
// 578.554 us; speedup vs baseline: 4.0467x; 1.1189x over previous
//
#include <hip/hip_runtime.h>
#include <math.h>

#define BB 16
#define CC 64
#define HH 128
#define WW 256
#define HWs 32768      // HH*WW
#define NN 524288      // BB*HH*WW
#define KMAX 8192
#define RCAP 65536     // tile-root list capacity per z
#define INV 0xFFFFFFFFu

// tile: full batch depth x 8h x 32w = 4096 voxels, 512 threads
#define TILE_H 8
#define TILE_W 32
#define TVOX 4096
#define TPB 512
#define NROWS 128      // BB * TILE_H rows of 32 w-bits
#define NWEDGE 14336   // 7 internal w-boundaries * 16b * 128h
#define NHEDGE 61440   // 15 internal h-boundaries * 16b * 256w
#define NEDGE  75776

// ---- workspace layout (bytes) ----
#define OFF_CMEAN    0                                   // f32 [3][NN]
#define OFF_PARENT   (OFF_CMEAN   + 3*NN*4)              // u32 [3][NN]
#define OFF_DENSE    (OFF_PARENT  + 3*NN*4)              // u32 [3][NN] (sparse: only roots)
#define OFF_ROOTLIST (OFF_DENSE   + 3*NN*4)              // u32 [3][RCAP] (not zeroed)
#define OFF_COUNTS   (OFF_ROOTLIST+ 3*RCAP*4)            // i32 [3][BB][KMAX]   <- zeroed from here
#define OFF_ROOTLAB  (OFF_COUNTS  + 3*BB*KMAX*4)         // u32 [3][KMAX]
#define OFF_MMKEY    (OFF_ROOTLAB + 3*KMAX*4)            // u32 [3][BB][2] (~minkey,maxkey), both atomicMax
#define OFF_K        (OFF_MMKEY   + 3*BB*2*4)            // u32 [3] (+pad)
#define OFF_RCNT     (OFF_K       + 16)                  // u32 [3] (+pad)
#define OFF_BEST     (OFF_RCNT    + 16)                  // u32 [3][BB]
#define OFF_CENT     (OFF_BEST    + 3*BB*4)              // i32 [3][BB][3]
#define OFF_END      (OFF_CENT    + 3*BB*3*4)

// monotone float<->uint key (order-preserving incl. negatives)
__device__ __forceinline__ unsigned f2key(float f) {
    unsigned u = __float_as_uint(f);
    return (u & 0x80000000u) ? ~u : (u | 0x80000000u);
}
__device__ __forceinline__ float key2f(unsigned k) {
    unsigned u = (k & 0x80000000u) ? (k ^ 0x80000000u) : ~k;
    return __uint_as_float(u);
}

// ---- union-find, links always point to LARGER index => root = max linear idx ----
__device__ unsigned uf_find(unsigned* p, unsigned i) {
    while (true) {
        unsigned pi = ((volatile unsigned*)p)[i];
        if (pi == i) return i;
        unsigned gp = ((volatile unsigned*)p)[pi];
        if (gp != pi) ((volatile unsigned*)p)[i] = gp;  // path halving (monotone, safe)
        i = pi;
    }
}
__device__ void uf_union(unsigned* p, unsigned a, unsigned b) {
    while (true) {
        a = uf_find(p, a);
        b = uf_find(p, b);
        if (a == b) return;
        if (a < b) { unsigned t = a; a = b; b = t; }   // a = max root
        unsigned old = atomicCAS(&p[b], b, a);
        if (old == b) return;
        b = old;
    }
}

// ---- LDS union-find (same invariants, shared-memory atomics) ----
__device__ __forceinline__ unsigned lfind(unsigned* p, unsigned i) {
    while (true) {
        unsigned pi = ((volatile unsigned*)p)[i];
        if (pi == i) return i;
        unsigned gp = ((volatile unsigned*)p)[pi];
        if (gp != pi) ((volatile unsigned*)p)[i] = gp;
        i = pi;
    }
}
__device__ void lunion(unsigned* p, unsigned a, unsigned b) {
    while (true) {
        a = lfind(p, a);
        b = lfind(p, b);
        if (a == b) return;
        if (a < b) { unsigned t = a; a = b; b = t; }
        unsigned old = atomicCAS(&p[b], b, a);
        if (old == b) return;
        b = old;
    }
}

// channel mean + per-sample min/max. Each thread owns TWO element columns
// (hw4, hw4+1024) with 4 independent c-group accumulators EACH (per-element
// summation order identical to previous round => bit-identical cmean).
// 8 dwordx4 loads in flight per thread for MLP against ~900cy HBM latency.
__global__ void k_cmean(const float* __restrict__ x0, const float* __restrict__ x1,
                        const float* __restrict__ x2, float* __restrict__ cmean,
                        unsigned* __restrict__ mmkey) {
    int z = blockIdx.z, b = blockIdx.y, t = threadIdx.x;
    const float* x = (z == 0) ? x0 : (z == 1) ? x1 : x2;
    int hwA = blockIdx.x * 2048 + t * 4;
    const float* pxA = x + (size_t)b * CC * HWs + hwA;
    const float* pxB = pxA + 1024;
    float4 a0 = make_float4(0.f, 0.f, 0.f, 0.f), a1 = a0, a2 = a0, a3 = a0;
    float4 c0 = a0, c1 = a0, c2 = a0, c3 = a0;
#pragma unroll
    for (int c = 0; c < CC; c += 4) {
        float4 va0 = *reinterpret_cast<const float4*>(pxA + (size_t)(c + 0) * HWs);
        float4 vb0 = *reinterpret_cast<const float4*>(pxB + (size_t)(c + 0) * HWs);
        float4 va1 = *reinterpret_cast<const float4*>(pxA + (size_t)(c + 1) * HWs);
        float4 vb1 = *reinterpret_cast<const float4*>(pxB + (size_t)(c + 1) * HWs);
        float4 va2 = *reinterpret_cast<const float4*>(pxA + (size_t)(c + 2) * HWs);
        float4 vb2 = *reinterpret_cast<const float4*>(pxB + (size_t)(c + 2) * HWs);
        float4 va3 = *reinterpret_cast<const float4*>(pxA + (size_t)(c + 3) * HWs);
        float4 vb3 = *reinterpret_cast<const float4*>(pxB + (size_t)(c + 3) * HWs);
        a0.x += va0.x; a0.y += va0.y; a0.z += va0.z; a0.w += va0.w;
        c0.x += vb0.x; c0.y += vb0.y; c0.z += vb0.z; c0.w += vb0.w;
        a1.x += va1.x; a1.y += va1.y; a1.z += va1.z; a1.w += va1.w;
        c1.x += vb1.x; c1.y += vb1.y; c1.z += vb1.z; c1.w += vb1.w;
        a2.x += va2.x; a2.y += va2.y; a2.z += va2.z; a2.w += va2.w;
        c2.x += vb2.x; c2.y += vb2.y; c2.z += vb2.z; c2.w += vb2.w;
        a3.x += va3.x; a3.y += va3.y; a3.z += va3.z; a3.w += va3.w;
        c3.x += vb3.x; c3.y += vb3.y; c3.z += vb3.z; c3.w += vb3.w;
    }
    const float inv = 1.f / 64.f;   // /64 exact pow2
    float4 sA, sB;
    sA.x = ((a0.x + a1.x) + (a2.x + a3.x)) * inv;
    sA.y = ((a0.y + a1.y) + (a2.y + a3.y)) * inv;
    sA.z = ((a0.z + a1.z) + (a2.z + a3.z)) * inv;
    sA.w = ((a0.w + a1.w) + (a2.w + a3.w)) * inv;
    sB.x = ((c0.x + c1.x) + (c2.x + c3.x)) * inv;
    sB.y = ((c0.y + c1.y) + (c2.y + c3.y)) * inv;
    sB.z = ((c0.z + c1.z) + (c2.z + c3.z)) * inv;
    sB.w = ((c0.w + c1.w) + (c2.w + c3.w)) * inv;
    float* cm = cmean + (size_t)z * NN + (size_t)b * HWs + hwA;
    *reinterpret_cast<float4*>(cm) = sA;
    *reinterpret_cast<float4*>(cm + 1024) = sB;

    float mn = fminf(fminf(fminf(sA.x, sA.y), fminf(sA.z, sA.w)),
                     fminf(fminf(sB.x, sB.y), fminf(sB.z, sB.w)));
    float mx = fmaxf(fmaxf(fmaxf(sA.x, sA.y), fmaxf(sA.z, sA.w)),
                     fmaxf(fmaxf(sB.x, sB.y), fmaxf(sB.z, sB.w)));
    for (int o = 32; o; o >>= 1) {
        mn = fminf(mn, __shfl_down(mn, o));
        mx = fmaxf(mx, __shfl_down(mx, o));
    }
    __shared__ float smn[4], smx[4];
    int wid = t >> 6, lane = t & 63;
    if (lane == 0) { smn[wid] = mn; smx[wid] = mx; }
    __syncthreads();
    if (t == 0) {
        mn = fminf(fminf(smn[0], smn[1]), fminf(smn[2], smn[3]));
        mx = fmaxf(fmaxf(smx[0], smx[1]), fmaxf(smx[2], smx[3]));
        atomicMax(&mmkey[(z * BB + b) * 2 + 0], ~f2key(mn));
        atomicMax(&mmkey[(z * BB + b) * 2 + 1], f2key(mx));
    }
}

// fused: normalize -> mask -> LOCAL run-based CCL over a [16b x 8h x 32w] tile.
// 512 threads (8 phases). Also emits a compacted global list of tile-root
// voxel indices so the downstream compress pass touches only roots, not NN.
__global__ void __launch_bounds__(TPB) k_mask_ccl(const float* __restrict__ cmean,
                                                  const unsigned* __restrict__ mmkey,
                                                  unsigned* __restrict__ parent_all,
                                                  unsigned* __restrict__ rootlist,
                                                  unsigned* __restrict__ rootcnt) {
    int z = blockIdx.z;
    int h0 = blockIdx.y * TILE_H;
    int w0 = blockIdx.x * TILE_W;
    int t = threadIdx.x;
    int lane = t & 63;
    __shared__ unsigned sp[TVOX];
    __shared__ unsigned rowmask[NROWS];
    __shared__ float smn[BB], smx[BB];
    __shared__ unsigned lcnt, sbase;
    if (t == 0) lcnt = 0;
    if (t < BB) {
        smn[t] = key2f(~mmkey[(z * BB + t) * 2 + 0]);
        smx[t] = key2f(mmkey[(z * BB + t) * 2 + 1]);
    }
    __syncthreads();
#pragma unroll
    for (int ph = 0; ph < TVOX / TPB; ph++) {
        int li = ph * TPB + t;
        int lb = li >> 8, lh = (li >> 5) & 7, lw = li & 31;
        unsigned gi = lb * HWs + (h0 + lh) * WW + (w0 + lw);
        float c = cmean[(size_t)z * NN + gi];
        bool mkd = (c - smn[lb]) / (smx[lb] - smn[lb]) >= 0.4f;
        unsigned long long bal = __ballot(mkd);
        unsigned m = (lane < 32) ? (unsigned)bal : (unsigned)(bal >> 32);
        int row = li >> 5;
        if ((lane & 31) == 0) rowmask[row] = m;
        unsigned v = INV;
        if (mkd) {
            int j = __ffsll(~((unsigned long long)m >> lw)) - 1;  // trailing-ones >=1
            v = (unsigned)((row << 5) + lw + j - 1);              // run root (run max)
        }
        sp[li] = v;
    }
    __syncthreads();
#pragma unroll
    for (int ph = 0; ph < TVOX / TPB; ph++) {
        int li = ph * TPB + t;
        int row = li >> 5, lw = li & 31;
        unsigned m = rowmask[row];
        if (!((m >> lw) & 1)) continue;
        int lh = row & 7;
        if (lh < TILE_H - 1) {                       // h-edge, row -> row+1
            unsigned m2 = rowmask[row + 1];
            unsigned ov = m & m2;
            bool leader = ((ov >> lw) & 1) && (lw == 0 || !((ov >> (lw - 1)) & 1));
            if (leader) {
                int j2 = __ffsll(~((unsigned long long)m2 >> lw)) - 1;
                lunion(sp, sp[li], (unsigned)(((row + 1) << 5) + lw + j2 - 1));
            }
        }
        if (row < NROWS - 8) {                       // b-edge, row -> row+8
            unsigned m2 = rowmask[row + 8];
            unsigned ov = m & m2;
            bool leader = ((ov >> lw) & 1) && (lw == 0 || !((ov >> (lw - 1)) & 1));
            if (leader) {
                int j2 = __ffsll(~((unsigned long long)m2 >> lw)) - 1;
                lunion(sp, sp[li], (unsigned)(((row + 8) << 5) + lw + j2 - 1));
            }
        }
    }
    __syncthreads();
    // pointer-jump flatten: tree static now; races only move entries rootward
#pragma unroll
    for (int it = 0; it < 4; it++) {
#pragma unroll
        for (int ph = 0; ph < TVOX / TPB; ph++) {
            int li = ph * TPB + t;
            unsigned v = sp[li];
            if (v != INV) {
                unsigned w = sp[v];
                if (w != v) sp[li] = w;
            }
        }
    }
    __syncthreads();
    unsigned myroot[TVOX / TPB];
    unsigned myoff[TVOX / TPB];
    int nmy = 0;
#pragma unroll
    for (int ph = 0; ph < TVOX / TPB; ph++) {
        int li = ph * TPB + t;
        int lb = li >> 8, lh = (li >> 5) & 7, lw = li & 31;
        unsigned gi = lb * HWs + (h0 + lh) * WW + (w0 + lw);
        unsigned v = sp[li];
        if (v != INV) {
            unsigned r = v;
            while (sp[r] != r) r = sp[r];           // short after flatten
            int rb = r >> 8, rh = (r >> 5) & 7, rw = r & 31;
            v = rb * HWs + (h0 + rh) * WW + (w0 + rw);
            if (r == (unsigned)li) {                // tile root -> record
                myroot[nmy] = gi;
                myoff[nmy] = atomicAdd(&lcnt, 1u);
                nmy++;
            }
        }
        parent_all[(size_t)z * NN + gi] = v;
    }
    __syncthreads();
    if (t == 0) sbase = atomicAdd(&rootcnt[z], lcnt);
    __syncthreads();
    for (int k = 0; k < nmy; k++) {
        unsigned idx = sbase + myoff[k];
        if (idx < RCAP) rootlist[(size_t)z * RCAP + idx] = myroot[k];
    }
}

// global unions only across tile boundaries (tile-root handles), run-leader dedup
__global__ void k_merge_bnd(unsigned* __restrict__ parent_all) {
    int z = blockIdx.y;
    unsigned* p = parent_all + (size_t)z * NN;
    int e = blockIdx.x * 256 + threadIdx.x;
    if (e >= NEDGE) return;
    unsigned i, j;
    bool lead = true;
    if (e < NWEDGE) {
        int k = e % 7, rest = e / 7;           // rest = b*128 + h
        int h = rest & (HH - 1), b = rest >> 7;
        int w = k * TILE_W + (TILE_W - 1);
        i = b * HWs + h * WW + w; j = i + 1;
        if ((h & (TILE_H - 1)) != 0)           // prev-h pair in same tiles?
            if (p[i - WW] != INV && p[j - WW] != INV) lead = false;
    } else {
        int e2 = e - NWEDGE;
        int k = e2 % 15, rest = e2 / 15;       // rest = b*256 + w
        int w = rest & (WW - 1), b = rest >> 8;
        int h = k * TILE_H + (TILE_H - 1);
        i = b * HWs + h * WW + w; j = i + WW;
        if ((w & (TILE_W - 1)) != 0)
            if (p[i - 1] != INV && p[j - 1] != INV) lead = false;
    }
    if (lead) {
        unsigned pi = p[i], pj = p[j];
        if (pi != INV && pj != INV) uf_union(p, pi, pj);
    }
}

// compress ONLY tile roots (p[t] -> global root) + dense-id the global roots.
// After this, root(voxel i) == p[p[i]] exactly, with no NN-wide write pass.
__global__ void k_rootcompress(unsigned* __restrict__ parent_all,
                               const unsigned* __restrict__ rootlist,
                               const unsigned* __restrict__ rootcnt,
                               unsigned* __restrict__ dense_all,
                               unsigned* __restrict__ rootlab, unsigned* __restrict__ Kc) {
    int z = blockIdx.y;
    unsigned* p = parent_all + (size_t)z * NN;
    unsigned cnt = rootcnt[z]; if (cnt > RCAP) cnt = RCAP;
    for (unsigned j = blockIdx.x * 256 + threadIdx.x; j < cnt; j += gridDim.x * 256) {
        unsigned r = rootlist[(size_t)z * RCAP + j];
        unsigned g = uf_find(p, r);
        p[r] = g;
        if (g == r) {
            unsigned id = atomicAdd(&Kc[z], 1u);
            if (id >= KMAX) id = KMAX - 1;   // never expected
            dense_all[(size_t)z * NN + g] = id;
            rootlab[z * KMAX + id] = g;
        }
    }
}

// per-slice per-component counts, wave-aggregated atomics; root = p[p[i]]
__global__ void k_count(const unsigned* __restrict__ parent_all,
                        const unsigned* __restrict__ dense_all, int* __restrict__ counts) {
    int z = blockIdx.y;
    const unsigned* p = parent_all + (size_t)z * NN;
    const unsigned* d = dense_all + (size_t)z * NN;
    int i = blockIdx.x * 256 + threadIdx.x;
    int b = i >> 15;   // uniform across the wave (64 | HWs)
    unsigned pi = p[i];
    bool valid = (pi != INV);
    int id = valid ? (int)d[p[pi]] : -1;
    int lane = threadIdx.x & 63;
    int* crow = counts + ((size_t)z * BB + b) * KMAX;
    unsigned long long rem = __ballot(valid);
    while (rem) {
        int leader = __ffsll(rem) - 1;
        int lid = __shfl(id, leader);
        unsigned long long m = __ballot(valid && id == lid) & rem;
        if (lane == leader) atomicAdd(&crow[lid], (int)__popcll(m));
        rem &= ~m;
    }
}

// per-slice argmax: max count, tie -> smallest root label (== reference argmax semantics)
__global__ void k_best(const int* __restrict__ counts, const unsigned* __restrict__ rootlab,
                       const unsigned* __restrict__ Kc, unsigned* __restrict__ best) {
    int z = blockIdx.y, b = blockIdx.x, t = threadIdx.x;
    const int* crow = counts + ((size_t)z * BB + b) * KMAX;
    const unsigned* rl = rootlab + z * KMAX;
    unsigned K = Kc[z]; if (K > KMAX) K = KMAX;
    int bc = -1; unsigned brl = INV; int bj = 0;
    for (unsigned j = t; j < K; j += blockDim.x) {
        int c = crow[j]; unsigned r = rl[j];
        if (c > bc || (c == bc && r < brl)) { bc = c; brl = r; bj = (int)j; }
    }
    __shared__ int sc[256]; __shared__ unsigned sr[256]; __shared__ int sj[256];
    sc[t] = bc; sr[t] = brl; sj[t] = bj;
    __syncthreads();
    for (int o = 128; o; o >>= 1) {
        if (t < o) {
            int c2 = sc[t + o]; unsigned r2 = sr[t + o];
            if (c2 > sc[t] || (c2 == sc[t] && r2 < sr[t])) { sc[t] = c2; sr[t] = r2; sj[t] = sj[t + o]; }
        }
        __syncthreads();
    }
    if (t == 0) best[z * BB + b] = (unsigned)sj[0];
}

// masked normalized output + integer centroid sums; root = p[p[i]]
__global__ void k_result(const float* __restrict__ cmean, const unsigned* __restrict__ parent_all,
                         const unsigned* __restrict__ dense_all, const unsigned* __restrict__ mmkey,
                         const unsigned* __restrict__ best, float* __restrict__ out,
                         int* __restrict__ cent) {
    int z = blockIdx.y;
    int i = blockIdx.x * 256 + threadIdx.x;
    int b = i >> 15;
    const unsigned* p = parent_all + (size_t)z * NN;
    unsigned pi = p[i];
    bool big = false;
    if (pi != INV) big = (dense_all[(size_t)z * NN + p[pi]] == best[z * BB + b]);
    float mn = key2f(~mmkey[(z * BB + b) * 2 + 0]);
    float mx = key2f(mmkey[(z * BB + b) * 2 + 1]);
    float c = cmean[(size_t)z * NN + i];
    float v = (c - mn) / (mx - mn);
    out[32 + (size_t)z * NN + i] = big ? v : 0.f;

    int c1 = big ? 1 : 0;
    int ch = big ? ((i >> 8) & (HH - 1)) : 0;
    int cw = big ? (i & (WW - 1)) : 0;
    for (int o = 32; o; o >>= 1) {
        c1 += __shfl_down(c1, o); ch += __shfl_down(ch, o); cw += __shfl_down(cw, o);
    }
    __shared__ int s0[4], s1[4], s2[4];
    int wid = threadIdx.x >> 6, lane = threadIdx.x & 63;
    if (lane == 0) { s0[wid] = c1; s1[wid] = ch; s2[wid] = cw; }
    __syncthreads();
    if (threadIdx.x == 0) {
        c1 = s0[0] + s0[1] + s0[2] + s0[3];
        ch = s1[0] + s1[1] + s1[2] + s1[3];
        cw = s2[0] + s2[1] + s2[2] + s2[3];
        int* ct = cent + (z * BB + b) * 3;
        atomicAdd(&ct[0], c1); atomicAdd(&ct[1], ch); atomicAdd(&ct[2], cw);
    }
}

__global__ void k_final(const int* __restrict__ cent, float* __restrict__ out) {
    int b = threadIdx.x;
    if (b >= BB) return;
    const float PI = (float)M_PI;  // f32(np.pi)
    float th[3], ph[3];
    for (int z = 0; z < 3; z++) {
        const int* ct = cent + (z * BB + b) * 3;
        float cnt = (float)ct[0];
        float hm = (float)ct[1] / cnt;   // integer sums exact in f32 (< 2^24)
        float wm = (float)ct[2] / cnt;
        ph[z] = (0.5f - hm / (float)HH) * PI;
        th[z] = (wm / (float)WW - 0.5f) * 2.0f * PI;
    }
    auto dist = [PI](float t1, float p1, float t2, float p2) {
        float cosd = sinf(t1) * sinf(t2) + cosf(t1) * cosf(t2) * cosf(p1 - p2);
        float d = acosf(cosd);
        if (isnan(d)) d = 0.f;           // jnp.nan_to_num semantics
        return d / PI;
    };
    out[b]      = dist(th[0], ph[0], th[1], ph[1]);
    out[BB + b] = dist(th[1], ph[1], th[2], ph[2]);
}

extern "C" void kernel_launch(void* const* d_in, const int* in_sizes, int n_in,
                              void* d_out, int out_size, void* d_ws, size_t ws_size,
                              hipStream_t stream) {
    const float* x0 = (const float*)d_in[0];
    const float* x1 = (const float*)d_in[1];
    const float* x2 = (const float*)d_in[2];
    float* out = (float*)d_out;
    char* ws = (char*)d_ws;
    float*    cmean    = (float*)(ws + OFF_CMEAN);
    unsigned* parent   = (unsigned*)(ws + OFF_PARENT);
    unsigned* dense    = (unsigned*)(ws + OFF_DENSE);
    unsigned* rootlist = (unsigned*)(ws + OFF_ROOTLIST);
    int*      counts   = (int*)(ws + OFF_COUNTS);
    unsigned* rootlab  = (unsigned*)(ws + OFF_ROOTLAB);
    unsigned* mmkey    = (unsigned*)(ws + OFF_MMKEY);
    unsigned* Kc       = (unsigned*)(ws + OFF_K);
    unsigned* rootcnt  = (unsigned*)(ws + OFF_RCNT);
    unsigned* best     = (unsigned*)(ws + OFF_BEST);
    int*      cent     = (int*)(ws + OFF_CENT);

    hipMemsetAsync(ws + OFF_COUNTS, 0, OFF_END - OFF_COUNTS, stream);
    hipLaunchKernelGGL(k_cmean, dim3(HWs / 2048, BB, 3), dim3(256), 0, stream,
                       x0, x1, x2, cmean, mmkey);
    hipLaunchKernelGGL(k_mask_ccl, dim3(WW / TILE_W, HH / TILE_H, 3), dim3(TPB), 0, stream,
                       cmean, mmkey, parent, rootlist, rootcnt);
    hipLaunchKernelGGL(k_merge_bnd, dim3((NEDGE + 255) / 256, 3), dim3(256), 0, stream, parent);
    hipLaunchKernelGGL(k_rootcompress, dim3(32, 3), dim3(256), 0, stream,
                       parent, rootlist, rootcnt, dense, rootlab, Kc);
    hipLaunchKernelGGL(k_count, dim3(NN / 256, 3), dim3(256), 0, stream, parent, dense, counts);
    hipLaunchKernelGGL(k_best, dim3(BB, 3), dim3(256), 0, stream, counts, rootlab, Kc, best);
    hipLaunchKernelGGL(k_result, dim3(NN / 256, 3), dim3(256), 0, stream,
                       cmean, parent, dense, mmkey, best, out, cent);
    hipLaunchKernelGGL(k_final, dim3(1), dim3(64), 0, stream, cent, out);
}